// Round 7
// baseline (2102.308 us; speedup 1.0000x reference)
//
#include <hip/hip_runtime.h>

#define N_NODES 30000
#define N_EDGES 240000
#define NF 32
#define EF 16
#define HF 64
#define NC 8
#define NWG 1024
#define TPB 256

// wbuf layout (float offsets)
#define W_COMB 0      // [16][16] We @ Wem[64:128)
#define B_COMB 256    // [16]     bem + be@Wem[64:128)
#define W_NC   272    // [16][32] We @ Wnm[0:64)
#define B_VEC  784    // [32]     be @ Wnm[0:64)
#define W_SD   816    // [32][32] cols 0-15: Wn@Wem[0:64) ; cols 16-31: Wn@Wem[128:192)
#define W_NB   1840   // [32][32] Wn @ Wnm[64:128)   (== W_SD + 1024)
#define B_SD   2864   // [32]     [bn@WemS | bn@WemD]
#define B_NB   2896   // [32]     bnm + bn@Wnm[64:128)  (== B_SD + 32)
#define W_NF   2928   // [32][8]  Wn @ Wfc
#define B_NF   3184   // [8]      bfc + bn@Wfc
#define WBUF_N 3192

__device__ __forceinline__ float sigmoidf_(float x) {
  return 1.0f / (1.0f + __expf(-x));
}

// ---------------------------------------------------------------------------
__global__ void __launch_bounds__(256) hist_kernel(
    const int* __restrict__ dst, int* __restrict__ cnt) {
  int e = blockIdx.x * 256 + threadIdx.x;
  if (e < N_EDGES) atomicAdd(&cnt[dst[e]], 1);
}

// exclusive scan of cnt[30000] -> off[30001], cursor = copy of off
__global__ void __launch_bounds__(1024) scan_kernel(
    const int* __restrict__ cnt, int* __restrict__ off, int* __restrict__ cursor) {
  __shared__ int part[1024];
  int t = threadIdx.x;
  const int CH = (N_NODES + 1023) / 1024;   // 30
  int base = t * CH;
  int lc[CH];
  int sum = 0;
  for (int i = 0; i < CH; ++i) {
    int idx = base + i;
    lc[i] = (idx < N_NODES) ? cnt[idx] : 0;
    sum += lc[i];
  }
  part[t] = sum;
  __syncthreads();
  for (int ofs = 1; ofs < 1024; ofs <<= 1) {
    int v = (t >= ofs) ? part[t - ofs] : 0;
    __syncthreads();
    part[t] += v;
    __syncthreads();
  }
  int run = (t == 0) ? 0 : part[t - 1];
  for (int i = 0; i < CH; ++i) {
    int idx = base + i;
    if (idx < N_NODES) {
      off[idx] = run;
      cursor[idx] = run;
      run += lc[i];
    }
  }
  if (t == 1023) off[N_NODES] = part[1023];
}

__global__ void __launch_bounds__(256) scatter_kernel(
    const float* __restrict__ edge_feat, const int* __restrict__ src,
    const int* __restrict__ dst, int* __restrict__ cursor,
    unsigned short* __restrict__ src_s, unsigned short* __restrict__ dst_s,
    float* __restrict__ e_buf) {
  int e = blockIdx.x * 256 + threadIdx.x;
  if (e >= N_EDGES) return;
  int d = dst[e];
  int pos = atomicAdd(&cursor[d], 1);
  src_s[pos] = (unsigned short)src[e];
  dst_s[pos] = (unsigned short)d;
  const float4* ep = (const float4*)(edge_feat + (size_t)e * EF);
  float4* op = (float4*)(e_buf + (size_t)pos * EF);
  op[0] = ep[0]; op[1] = ep[1]; op[2] = ep[2]; op[3] = ep[3];
}

// bnd[w] = smallest n with off[n] >= w*E/NWG ; bnd[NWG] = N
__global__ void __launch_bounds__(1024) partition_kernel(
    const int* __restrict__ off, int* __restrict__ bnd) {
  for (int w = threadIdx.x; w <= NWG; w += 1024) {
    if (w == NWG) { bnd[w] = N_NODES; continue; }
    long long target = ((long long)w * N_EDGES) / NWG;
    int lo = 0, hi = N_NODES;
    while (lo < hi) {
      int mid = (lo + hi) >> 1;
      if ((long long)off[mid] < target) lo = mid + 1; else hi = mid;
    }
    bnd[w] = lo;
  }
}

// ---------------------------------------------------------------------------
__global__ void __launch_bounds__(256) precompute_kernel(
    const float* __restrict__ Wn, const float* __restrict__ bn,
    const float* __restrict__ We, const float* __restrict__ be,
    const float* __restrict__ Wem, const float* __restrict__ bem,
    const float* __restrict__ Wnm, const float* __restrict__ bnm,
    const float* __restrict__ Wfc, const float* __restrict__ bfc,
    float* __restrict__ wbuf) {
  int tid = threadIdx.x;
  {  // Wcomb
    int r = tid >> 4, c = tid & 15;
    float acc = 0.f;
    for (int j = 0; j < HF; ++j) acc = fmaf(We[r * HF + j], Wem[(HF + j) * EF + c], acc);
    wbuf[W_COMB + tid] = acc;
  }
  for (int idx = tid; idx < EF * NF; idx += 256) {  // Wnc
    int r = idx >> 5, c = idx & 31;
    float acc = 0.f;
    for (int j = 0; j < HF; ++j) acc = fmaf(We[r * HF + j], Wnm[j * NF + c], acc);
    wbuf[W_NC + idx] = acc;
  }
  for (int idx = tid; idx < NF * NF; idx += 256) {  // WSD
    int r = idx >> 5, c = idx & 31;
    float acc = 0.f;
    if (c < EF) {
      for (int j = 0; j < HF; ++j) acc = fmaf(Wn[r * HF + j], Wem[j * EF + c], acc);
    } else {
      int cc = c - EF;
      for (int j = 0; j < HF; ++j) acc = fmaf(Wn[r * HF + j], Wem[(2 * HF + j) * EF + cc], acc);
    }
    wbuf[W_SD + idx] = acc;
  }
  for (int idx = tid; idx < NF * NF; idx += 256) {  // WnB
    int r = idx >> 5, c = idx & 31;
    float acc = 0.f;
    for (int j = 0; j < HF; ++j) acc = fmaf(Wn[r * HF + j], Wnm[(HF + j) * NF + c], acc);
    wbuf[W_NB + idx] = acc;
  }
  if (tid < NF * NC) {  // Wnf
    int r = tid >> 3, c = tid & 7;
    float acc = 0.f;
    for (int j = 0; j < HF; ++j) acc = fmaf(Wn[r * HF + j], Wfc[j * NC + c], acc);
    wbuf[W_NF + tid] = acc;
  }
  if (tid < EF) {  // bcomb
    float acc = bem[tid];
    for (int j = 0; j < HF; ++j) acc = fmaf(be[j], Wem[(HF + j) * EF + tid], acc);
    wbuf[B_COMB + tid] = acc;
  }
  if (tid < NF) {  // bvec
    float acc = 0.f;
    for (int j = 0; j < HF; ++j) acc = fmaf(be[j], Wnm[j * NF + tid], acc);
    wbuf[B_VEC + tid] = acc;
  }
  if (tid < NF) {  // bSD
    float acc = 0.f;
    if (tid < EF) {
      for (int j = 0; j < HF; ++j) acc = fmaf(bn[j], Wem[j * EF + tid], acc);
    } else {
      int cc = tid - EF;
      for (int j = 0; j < HF; ++j) acc = fmaf(bn[j], Wem[(2 * HF + j) * EF + cc], acc);
    }
    wbuf[B_SD + tid] = acc;
  }
  if (tid < NF) {  // bNB
    float acc = bnm[tid];
    for (int j = 0; j < HF; ++j) acc = fmaf(bn[j], Wnm[(HF + j) * NF + tid], acc);
    wbuf[B_NB + tid] = acc;
  }
  if (tid < NC) {  // bnf
    float acc = bfc[tid];
    for (int j = 0; j < HF; ++j) acc = fmaf(bn[j], Wfc[j * NC + tid], acc);
    wbuf[B_NF + tid] = acc;
  }
}

// ---------------------------------------------------------------------------
// init: [P_s|P_d] = x@WSD + bSD (p=0) ; hpart = x@WnB + bNB (p=1)
// ---------------------------------------------------------------------------
__global__ void __launch_bounds__(256) init_proj_kernel(
    const float* __restrict__ node_feat, const float* __restrict__ wbuf,
    float* __restrict__ Ps, float* __restrict__ Pd, float* __restrict__ hpart) {
  __shared__ float sPRJ[2048];
  __shared__ float sPB[64];
  for (int i = threadIdx.x; i < 2048; i += 256) sPRJ[i] = wbuf[W_SD + i];
  if (threadIdx.x < 64) sPB[threadIdx.x] = wbuf[B_SD + threadIdx.x];
  __syncthreads();
  int gid = blockIdx.x * 256 + threadIdx.x;
  int n = gid >> 1, p = gid & 1;
  if (n >= N_NODES) return;
  float x[NF];
  const float4* xp = (const float4*)(node_feat + (size_t)n * NF);
#pragma unroll
  for (int k4 = 0; k4 < 8; ++k4) {
    float4 v = xp[k4];
    x[4 * k4] = v.x; x[4 * k4 + 1] = v.y; x[4 * k4 + 2] = v.z; x[4 * k4 + 3] = v.w;
  }
  const float* wbase = sPRJ + p * 1024;
  // j-outer: 4 outputs at a time (keeps registers low)
#pragma unroll
  for (int ob = 0; ob < 8; ++ob) {
    float4 acc = *(const float4*)(sPB + p * 32 + 4 * ob);
    for (int k = 0; k < NF; ++k) {
      float4 wv = *(const float4*)(wbase + k * NF + 4 * ob);
      acc.x = fmaf(x[k], wv.x, acc.x);
      acc.y = fmaf(x[k], wv.y, acc.y);
      acc.z = fmaf(x[k], wv.z, acc.z);
      acc.w = fmaf(x[k], wv.w, acc.w);
    }
    if (p == 0) {
      if (ob < 4) ((float4*)(Ps + (size_t)n * EF))[ob] = acc;
      else        ((float4*)(Pd + (size_t)n * EF))[ob - 4] = acc;
    } else {
      ((float4*)(hpart + (size_t)n * NF))[ob] = acc;
    }
  }
}

// ---------------------------------------------------------------------------
// Fused iteration i (1..11), e ping-pong (eA -> eB, NO intra-kernel barrier):
//   edge phase: eB[q] = sigmoid(bcomb + eA[q]@Wcomb + Ps[src] + Pd[dst])
//   node phase: z = hpart|deg*bvec + segsum(eA)@Wnc ; sig ; project next
//               Ps/Pd/hpart (j-outer, 4 outputs at a time).
// Slice-affine (bnd) so eA is HBM-fetched once; phases independent -> their
// memory latencies overlap across waves. __launch_bounds__(256,4) caps VGPR
// at 128 (4 blocks/CU, 16 waves/CU) — j-outer keeps natural usage below it.
// ---------------------------------------------------------------------------
__global__ void __launch_bounds__(TPB, 4) iter_kernel(
    const float* __restrict__ eA, float* __restrict__ eB,
    const unsigned short* __restrict__ src_s,
    const unsigned short* __restrict__ dst_s,
    const int* __restrict__ off, const int* __restrict__ bnd,
    const float* __restrict__ wbuf, float* __restrict__ hpart,
    const float* __restrict__ PsR, const float* __restrict__ PdR,
    float* __restrict__ PsW, float* __restrict__ PdW) {
  __shared__ float sW[WBUF_N];              // 12.8 KB
  const int tid = threadIdx.x, w = blockIdx.x;
  const int nstart = bnd[w], nend = bnd[w + 1];
  const int estart = off[nstart];
  const int eend = off[nend];
  const int nloc = nend - nstart;
  for (int i = tid; i < WBUF_N; i += TPB) sW[i] = wbuf[i];
  __syncthreads();

  // ---- edge phase (issues the random P gathers early; warms L2 with eA) ----
  for (int q = estart + tid; q < eend; q += TPB) {
    const int s = src_s[q], d = dst_s[q];
    const float4* ep  = (const float4*)(eA + (size_t)q * EF);
    const float4* psp = (const float4*)(PsR + (size_t)s * EF);
    const float4* pdp = (const float4*)(PdR + (size_t)d * EF);
    float4 e4[4]  = {ep[0], ep[1], ep[2], ep[3]};
    float4 ps4[4] = {psp[0], psp[1], psp[2], psp[3]};
    float4 pd4[4] = {pdp[0], pdp[1], pdp[2], pdp[3]};
    float e[16];
#pragma unroll
    for (int k4 = 0; k4 < 4; ++k4) {
      e[4 * k4] = e4[k4].x; e[4 * k4 + 1] = e4[k4].y;
      e[4 * k4 + 2] = e4[k4].z; e[4 * k4 + 3] = e4[k4].w;
    }
    float4* ob = (float4*)(eB + (size_t)q * EF);
#pragma unroll
    for (int i4 = 0; i4 < 4; ++i4) {
      float4 bc = *(const float4*)(sW + B_COMB + 4 * i4);
      float4 z;
      z.x = bc.x + ps4[i4].x + pd4[i4].x;
      z.y = bc.y + ps4[i4].y + pd4[i4].y;
      z.z = bc.z + ps4[i4].z + pd4[i4].z;
      z.w = bc.w + ps4[i4].w + pd4[i4].w;
#pragma unroll
      for (int k = 0; k < EF; ++k) {
        float4 wv = *(const float4*)(sW + W_COMB + k * EF + 4 * i4);
        z.x = fmaf(e[k], wv.x, z.x);
        z.y = fmaf(e[k], wv.y, z.y);
        z.z = fmaf(e[k], wv.z, z.z);
        z.w = fmaf(e[k], wv.w, z.w);
      }
      z.x = sigmoidf_(z.x); z.y = sigmoidf_(z.y);
      z.z = sigmoidf_(z.z); z.w = sigmoidf_(z.w);
      ob[i4] = z;
    }
  }

  // ---- node phase: 2 lanes/node ----
  const int p = tid & 1;
  for (int ln = tid >> 1; ln < nloc; ln += TPB / 2) {
    const int n = nstart + ln;
    const int o0 = off[n], o1 = off[n + 1];
    float s8[8] = {0, 0, 0, 0, 0, 0, 0, 0};
    const float* ebase = eA + 8 * p;
    int q = o0;
    for (; q + 2 <= o1; q += 2) {
      const float4* e0 = (const float4*)(ebase + (size_t)q * EF);
      const float4* e1 = (const float4*)(ebase + (size_t)(q + 1) * EF);
      float4 a0 = e0[0], b0 = e0[1], a1 = e1[0], b1 = e1[1];
      s8[0] += a0.x + a1.x; s8[1] += a0.y + a1.y;
      s8[2] += a0.z + a1.z; s8[3] += a0.w + a1.w;
      s8[4] += b0.x + b1.x; s8[5] += b0.y + b1.y;
      s8[6] += b0.z + b1.z; s8[7] += b0.w + b1.w;
    }
    if (q < o1) {
      const float4* e0 = (const float4*)(ebase + (size_t)q * EF);
      float4 a0 = e0[0], b0 = e0[1];
      s8[0] += a0.x; s8[1] += a0.y; s8[2] += a0.z; s8[3] += a0.w;
      s8[4] += b0.x; s8[5] += b0.y; s8[6] += b0.z; s8[7] += b0.w;
    }
    float z[NF];
    if (p == 0) {
      const float4* hp = (const float4*)(hpart + (size_t)n * NF);
#pragma unroll
      for (int j4 = 0; j4 < 8; ++j4) {
        float4 v = hp[j4];
        z[4 * j4] = v.x; z[4 * j4 + 1] = v.y; z[4 * j4 + 2] = v.z; z[4 * j4 + 3] = v.w;
      }
    } else {
      float dg = (float)(o1 - o0);
#pragma unroll
      for (int j = 0; j < NF; ++j) z[j] = dg * sW[B_VEC + j];
    }
#pragma unroll
    for (int k = 0; k < 8; ++k) {
      float v = s8[k];
      const float4* wr = (const float4*)(sW + W_NC + (8 * p + k) * NF);
#pragma unroll
      for (int j4 = 0; j4 < 8; ++j4) {
        float4 wv = wr[j4];
        z[4 * j4 + 0] = fmaf(v, wv.x, z[4 * j4 + 0]);
        z[4 * j4 + 1] = fmaf(v, wv.y, z[4 * j4 + 1]);
        z[4 * j4 + 2] = fmaf(v, wv.z, z[4 * j4 + 2]);
        z[4 * j4 + 3] = fmaf(v, wv.w, z[4 * j4 + 3]);
      }
    }
#pragma unroll
    for (int j = 0; j < NF; ++j) z[j] += __shfl_xor(z[j], 1, 64);
#pragma unroll
    for (int j = 0; j < NF; ++j) z[j] = sigmoidf_(z[j]);

    // projection, j-outer (4 outputs at a time; sig z[32] is the only big array)
    const float* wb = sW + W_SD + p * 1024;   // p=0: WSD ; p=1: WnB
#pragma unroll
    for (int ob = 0; ob < 8; ++ob) {
      float4 acc = *(const float4*)(sW + B_SD + p * 32 + 4 * ob);
      for (int k = 0; k < NF; ++k) {
        float4 wv = *(const float4*)(wb + k * NF + 4 * ob);
        acc.x = fmaf(z[k], wv.x, acc.x);
        acc.y = fmaf(z[k], wv.y, acc.y);
        acc.z = fmaf(z[k], wv.z, acc.z);
        acc.w = fmaf(z[k], wv.w, acc.w);
      }
      if (p == 0) {
        if (ob < 4) ((float4*)(PsW + (size_t)n * EF))[ob] = acc;
        else        ((float4*)(PdW + (size_t)n * EF))[ob - 4] = acc;
      } else {
        ((float4*)(hpart + (size_t)n * NF))[ob] = acc;
      }
    }
  }
}

// ---------------------------------------------------------------------------
// Final: node pass 12 + output head. Grid-wide 2 threads/node; reads e(12).
// ---------------------------------------------------------------------------
__global__ void __launch_bounds__(256) final12_kernel(
    const float* __restrict__ e_buf, const float* __restrict__ hpart,
    const int* __restrict__ off, const float* __restrict__ wbuf,
    float* __restrict__ out) {
  __shared__ float sW[WBUF_N];
  for (int i = threadIdx.x; i < WBUF_N; i += 256) sW[i] = wbuf[i];
  __syncthreads();
  int gid = blockIdx.x * 256 + threadIdx.x;
  int n = gid >> 1, p = gid & 1;
  if (n >= N_NODES) return;
  int o0 = off[n], o1 = off[n + 1];

  float s8[8] = {0, 0, 0, 0, 0, 0, 0, 0};
  for (int q = o0; q < o1; ++q) {
    const float4* ep = (const float4*)(e_buf + (size_t)q * EF + 8 * p);
    float4 a = ep[0], b = ep[1];
    s8[0] += a.x; s8[1] += a.y; s8[2] += a.z; s8[3] += a.w;
    s8[4] += b.x; s8[5] += b.y; s8[6] += b.z; s8[7] += b.w;
  }
  float z[NF];
  if (p == 0) {
    const float4* hp = (const float4*)(hpart + (size_t)n * NF);
#pragma unroll
    for (int j4 = 0; j4 < 8; ++j4) {
      float4 v = hp[j4];
      z[4 * j4] = v.x; z[4 * j4 + 1] = v.y; z[4 * j4 + 2] = v.z; z[4 * j4 + 3] = v.w;
    }
  } else {
    float dg = (float)(o1 - o0);
#pragma unroll
    for (int j = 0; j < NF; ++j) z[j] = dg * sW[B_VEC + j];
  }
#pragma unroll
  for (int k = 0; k < 8; ++k) {
    float v = s8[k];
    const float4* wr = (const float4*)(sW + W_NC + (8 * p + k) * NF);
#pragma unroll
    for (int j4 = 0; j4 < 8; ++j4) {
      float4 wv = wr[j4];
      z[4 * j4 + 0] = fmaf(v, wv.x, z[4 * j4 + 0]);
      z[4 * j4 + 1] = fmaf(v, wv.y, z[4 * j4 + 1]);
      z[4 * j4 + 2] = fmaf(v, wv.z, z[4 * j4 + 2]);
      z[4 * j4 + 3] = fmaf(v, wv.w, z[4 * j4 + 3]);
    }
  }
#pragma unroll
  for (int j = 0; j < NF; ++j) z[j] += __shfl_xor(z[j], 1, 64);
#pragma unroll
  for (int j = 0; j < NF; ++j) z[j] = sigmoidf_(z[j]);

  // head: out = sig @ Wnf + bnf; each lane does its 16 rows (constant indices).
  float o[NC];
#pragma unroll
  for (int c = 0; c < NC; ++c) o[c] = (p == 0) ? sW[B_NF + c] : 0.0f;
#pragma unroll
  for (int k = 0; k < 16; ++k) {
    float v = (p == 0) ? z[k] : z[16 + k];
    const float* wr = sW + W_NF + (16 * p + k) * NC;
#pragma unroll
    for (int c = 0; c < NC; ++c) o[c] = fmaf(v, wr[c], o[c]);
  }
#pragma unroll
  for (int c = 0; c < NC; ++c) o[c] += __shfl_xor(o[c], 1, 64);
  if (p == 0) {
    float4* op = (float4*)(out + (size_t)n * NC);
    op[0] = make_float4(o[0], o[1], o[2], o[3]);
    op[1] = make_float4(o[4], o[5], o[6], o[7]);
  }
}

// ---------------------------------------------------------------------------
extern "C" void kernel_launch(void* const* d_in, const int* in_sizes, int n_in,
                              void* d_out, int out_size, void* d_ws, size_t ws_size,
                              hipStream_t stream) {
  const float* node_feat = (const float*)d_in[0];
  const float* edge_feat = (const float*)d_in[1];
  const int*   src = (const int*)d_in[2];
  const int*   dst = (const int*)d_in[3];
  const float* Wn  = (const float*)d_in[4];
  const float* bn  = (const float*)d_in[5];
  const float* We  = (const float*)d_in[6];
  const float* be  = (const float*)d_in[7];
  const float* Wem = (const float*)d_in[8];
  const float* bem = (const float*)d_in[9];
  const float* Wnm = (const float*)d_in[10];
  const float* bnm = (const float*)d_in[11];
  const float* Wfc = (const float*)d_in[12];
  const float* bfc = (const float*)d_in[13];
  float* out = (float*)d_out;

  float* ws    = (float*)d_ws;
  float* eb0   = ws;                                   // 3,840,000 f
  float* eb1   = eb0 + (size_t)N_EDGES * EF;           // 3,840,000 f
  float* hpart = eb1 + (size_t)N_EDGES * EF;           //   960,000 f
  float* Ps0   = hpart + (size_t)N_NODES * NF;         //   480,000 f
  float* Ps1   = Ps0 + (size_t)N_NODES * EF;
  float* Pd0   = Ps1 + (size_t)N_NODES * EF;
  float* Pd1   = Pd0 + (size_t)N_NODES * EF;
  float* wbuf  = Pd1 + (size_t)N_NODES * EF;           //     4,096 f
  int* cnt     = (int*)(wbuf + 4096);                  //    30,000 i
  int* off     = cnt + N_NODES;                        //    30,001 i
  int* cursor  = off + N_NODES + 1;                    //    30,000 i
  int* bnd     = cursor + N_NODES;                     //  NWG+1 i
  unsigned short* src_s = (unsigned short*)(bnd + NWG + 1);     // 240,000 u16
  unsigned short* dst_s = src_s + N_EDGES;                      // 240,000 u16
  float* PsA[2] = {Ps0, Ps1};
  float* PdA[2] = {Pd0, Pd1};
  float* EB2[2] = {eb0, eb1};

  const int EBg = (N_EDGES + 255) / 256;       // 938
  const int NB2 = (2 * N_NODES + 255) / 256;   // 235

  // counting sort of edges by dst + partition + weight folding
  hipMemsetAsync(cnt, 0, (size_t)N_NODES * sizeof(int), stream);
  hist_kernel<<<EBg, 256, 0, stream>>>(dst, cnt);
  scan_kernel<<<1, 1024, 0, stream>>>(cnt, off, cursor);
  scatter_kernel<<<EBg, 256, 0, stream>>>(edge_feat, src, dst, cursor,
                                          src_s, dst_s, eb0);
  partition_kernel<<<1, 1024, 0, stream>>>(off, bnd);
  precompute_kernel<<<1, 256, 0, stream>>>(Wn, bn, We, be, Wem, bem,
                                           Wnm, bnm, Wfc, bfc, wbuf);
  init_proj_kernel<<<NB2, 256, 0, stream>>>(node_feat, wbuf, Ps1, Pd1, hpart);

  // iterations 1..11: e ping-pong (iter i reads EB2[(i-1)&1], writes EB2[i&1]);
  // P ping-pong (reads P[i&1], writes P[(i+1)&1]). Then node 12 + head.
  for (int i = 1; i <= 11; ++i) {
    iter_kernel<<<NWG, TPB, 0, stream>>>(
        EB2[(i - 1) & 1], EB2[i & 1], src_s, dst_s, off, bnd, wbuf, hpart,
        PsA[i & 1], PdA[i & 1], PsA[(i + 1) & 1], PdA[(i + 1) & 1]);
  }
  final12_kernel<<<NB2, 256, 0, stream>>>(EB2[1], hpart, off, wbuf, out);
}

// Round 8
// 622.587 us; speedup vs baseline: 3.3767x; 3.3767x over previous
//
#include <hip/hip_runtime.h>

#define N_NODES 30000
#define N_EDGES 240000
#define NF 32
#define EF 16
#define HF 64
#define NC 8
#define NWG 1024
#define TPB 256
#define MAXN_CHUNK 80   // nodes processed per LDS-sig chunk (nloc~30 typ, 12-sigma safe)

// wbuf layout (float offsets)
#define W_COMB 0      // [16][16] We @ Wem[64:128)
#define B_COMB 256    // [16]     bem + be@Wem[64:128)
#define W_NC   272    // [16][32] We @ Wnm[0:64)
#define B_VEC  784    // [32]     be @ Wnm[0:64)
#define W_SD   816    // [32][32] cols 0-15: Wn@Wem[0:64) ; cols 16-31: Wn@Wem[128:192)
#define W_NB   1840   // [32][32] Wn @ Wnm[64:128)   (== W_SD + 1024)
#define B_SD   2864   // [32]     [bn@WemS | bn@WemD]
#define B_NB   2896   // [32]     bnm + bn@Wnm[64:128)  (== B_SD + 32)
#define W_NF   2928   // [32][8]  Wn @ Wfc
#define B_NF   3184   // [8]      bfc + bn@Wfc
#define WBUF_N 3192

#define SIG_LD 36     // LDS row stride for sig table (16B aligned); col 32 = deg

__device__ __forceinline__ float sigmoidf_(float x) {
  return 1.0f / (1.0f + __expf(-x));
}

// ---------------------------------------------------------------------------
__global__ void __launch_bounds__(256) hist_kernel(
    const int* __restrict__ dst, int* __restrict__ cnt) {
  int e = blockIdx.x * 256 + threadIdx.x;
  if (e < N_EDGES) atomicAdd(&cnt[dst[e]], 1);
}

// exclusive scan of cnt[30000] -> off[30001], cursor = copy of off
__global__ void __launch_bounds__(1024) scan_kernel(
    const int* __restrict__ cnt, int* __restrict__ off, int* __restrict__ cursor) {
  __shared__ int part[1024];
  int t = threadIdx.x;
  const int CH = (N_NODES + 1023) / 1024;   // 30
  int base = t * CH;
  int lc[CH];
  int sum = 0;
  for (int i = 0; i < CH; ++i) {
    int idx = base + i;
    lc[i] = (idx < N_NODES) ? cnt[idx] : 0;
    sum += lc[i];
  }
  part[t] = sum;
  __syncthreads();
  for (int ofs = 1; ofs < 1024; ofs <<= 1) {
    int v = (t >= ofs) ? part[t - ofs] : 0;
    __syncthreads();
    part[t] += v;
    __syncthreads();
  }
  int run = (t == 0) ? 0 : part[t - 1];
  for (int i = 0; i < CH; ++i) {
    int idx = base + i;
    if (idx < N_NODES) {
      off[idx] = run;
      cursor[idx] = run;
      run += lc[i];
    }
  }
  if (t == 1023) off[N_NODES] = part[1023];
}

__global__ void __launch_bounds__(256) scatter_kernel(
    const float* __restrict__ edge_feat, const int* __restrict__ src,
    const int* __restrict__ dst, int* __restrict__ cursor,
    unsigned short* __restrict__ src_s, unsigned short* __restrict__ dst_s,
    float* __restrict__ e_buf) {
  int e = blockIdx.x * 256 + threadIdx.x;
  if (e >= N_EDGES) return;
  int d = dst[e];
  int pos = atomicAdd(&cursor[d], 1);
  src_s[pos] = (unsigned short)src[e];
  dst_s[pos] = (unsigned short)d;
  const float4* ep = (const float4*)(edge_feat + (size_t)e * EF);
  float4* op = (float4*)(e_buf + (size_t)pos * EF);
  op[0] = ep[0]; op[1] = ep[1]; op[2] = ep[2]; op[3] = ep[3];
}

// bnd[w] = smallest n with off[n] >= w*E/NWG ; bnd[NWG] = N
__global__ void __launch_bounds__(1024) partition_kernel(
    const int* __restrict__ off, int* __restrict__ bnd) {
  for (int w = threadIdx.x; w <= NWG; w += 1024) {
    if (w == NWG) { bnd[w] = N_NODES; continue; }
    long long target = ((long long)w * N_EDGES) / NWG;
    int lo = 0, hi = N_NODES;
    while (lo < hi) {
      int mid = (lo + hi) >> 1;
      if ((long long)off[mid] < target) lo = mid + 1; else hi = mid;
    }
    bnd[w] = lo;
  }
}

// ---------------------------------------------------------------------------
__global__ void __launch_bounds__(256) precompute_kernel(
    const float* __restrict__ Wn, const float* __restrict__ bn,
    const float* __restrict__ We, const float* __restrict__ be,
    const float* __restrict__ Wem, const float* __restrict__ bem,
    const float* __restrict__ Wnm, const float* __restrict__ bnm,
    const float* __restrict__ Wfc, const float* __restrict__ bfc,
    float* __restrict__ wbuf) {
  int tid = threadIdx.x;
  {  // Wcomb
    int r = tid >> 4, c = tid & 15;
    float acc = 0.f;
    for (int j = 0; j < HF; ++j) acc = fmaf(We[r * HF + j], Wem[(HF + j) * EF + c], acc);
    wbuf[W_COMB + tid] = acc;
  }
  for (int idx = tid; idx < EF * NF; idx += 256) {  // Wnc
    int r = idx >> 5, c = idx & 31;
    float acc = 0.f;
    for (int j = 0; j < HF; ++j) acc = fmaf(We[r * HF + j], Wnm[j * NF + c], acc);
    wbuf[W_NC + idx] = acc;
  }
  for (int idx = tid; idx < NF * NF; idx += 256) {  // WSD
    int r = idx >> 5, c = idx & 31;
    float acc = 0.f;
    if (c < EF) {
      for (int j = 0; j < HF; ++j) acc = fmaf(Wn[r * HF + j], Wem[j * EF + c], acc);
    } else {
      int cc = c - EF;
      for (int j = 0; j < HF; ++j) acc = fmaf(Wn[r * HF + j], Wem[(2 * HF + j) * EF + cc], acc);
    }
    wbuf[W_SD + idx] = acc;
  }
  for (int idx = tid; idx < NF * NF; idx += 256) {  // WnB
    int r = idx >> 5, c = idx & 31;
    float acc = 0.f;
    for (int j = 0; j < HF; ++j) acc = fmaf(Wn[r * HF + j], Wnm[(HF + j) * NF + c], acc);
    wbuf[W_NB + idx] = acc;
  }
  if (tid < NF * NC) {  // Wnf
    int r = tid >> 3, c = tid & 7;
    float acc = 0.f;
    for (int j = 0; j < HF; ++j) acc = fmaf(Wn[r * HF + j], Wfc[j * NC + c], acc);
    wbuf[W_NF + tid] = acc;
  }
  if (tid < EF) {  // bcomb
    float acc = bem[tid];
    for (int j = 0; j < HF; ++j) acc = fmaf(be[j], Wem[(HF + j) * EF + tid], acc);
    wbuf[B_COMB + tid] = acc;
  }
  if (tid < NF) {  // bvec
    float acc = 0.f;
    for (int j = 0; j < HF; ++j) acc = fmaf(be[j], Wnm[j * NF + tid], acc);
    wbuf[B_VEC + tid] = acc;
  }
  if (tid < NF) {  // bSD
    float acc = 0.f;
    if (tid < EF) {
      for (int j = 0; j < HF; ++j) acc = fmaf(bn[j], Wem[j * EF + tid], acc);
    } else {
      int cc = tid - EF;
      for (int j = 0; j < HF; ++j) acc = fmaf(bn[j], Wem[(2 * HF + j) * EF + cc], acc);
    }
    wbuf[B_SD + tid] = acc;
  }
  if (tid < NF) {  // bNB
    float acc = bnm[tid];
    for (int j = 0; j < HF; ++j) acc = fmaf(bn[j], Wnm[(HF + j) * NF + tid], acc);
    wbuf[B_NB + tid] = acc;
  }
  if (tid < NC) {  // bnf
    float acc = bfc[tid];
    for (int j = 0; j < HF; ++j) acc = fmaf(bn[j], Wfc[j * NC + tid], acc);
    wbuf[B_NF + tid] = acc;
  }
}

// ---------------------------------------------------------------------------
// init: [P_s|P_d] = x@WSD + bSD (p=0) ; hpart* = x@WnB + bNB + deg*bvec (p=1)
// ---------------------------------------------------------------------------
__global__ void __launch_bounds__(256) init_proj_kernel(
    const float* __restrict__ node_feat, const float* __restrict__ wbuf,
    const int* __restrict__ off,
    float* __restrict__ Ps, float* __restrict__ Pd, float* __restrict__ hpart) {
  __shared__ float sPRJ[2048];
  __shared__ float sPB[64];
  __shared__ float sBV[32];
  for (int i = threadIdx.x; i < 2048; i += 256) sPRJ[i] = wbuf[W_SD + i];
  if (threadIdx.x < 64) sPB[threadIdx.x] = wbuf[B_SD + threadIdx.x];
  if (threadIdx.x < 32) sBV[threadIdx.x] = wbuf[B_VEC + threadIdx.x];
  __syncthreads();
  int gid = blockIdx.x * 256 + threadIdx.x;
  int n = gid >> 1, p = gid & 1;
  if (n >= N_NODES) return;
  float dg = (float)(off[n + 1] - off[n]);
  float x[NF];
  const float4* xp = (const float4*)(node_feat + (size_t)n * NF);
#pragma unroll
  for (int k4 = 0; k4 < 8; ++k4) {
    float4 v = xp[k4];
    x[4 * k4] = v.x; x[4 * k4 + 1] = v.y; x[4 * k4 + 2] = v.z; x[4 * k4 + 3] = v.w;
  }
  const float* wbase = sPRJ + p * 1024;
#pragma unroll 1
  for (int ob = 0; ob < 8; ++ob) {
    float4 acc = *(const float4*)(sPB + p * 32 + 4 * ob);
    if (p == 1) {   // fold deg*bvec into hpart
      float4 bv = *(const float4*)(sBV + 4 * ob);
      acc.x = fmaf(dg, bv.x, acc.x); acc.y = fmaf(dg, bv.y, acc.y);
      acc.z = fmaf(dg, bv.z, acc.z); acc.w = fmaf(dg, bv.w, acc.w);
    }
#pragma unroll
    for (int k = 0; k < NF; ++k) {
      float4 wv = *(const float4*)(wbase + k * NF + 4 * ob);
      acc.x = fmaf(x[k], wv.x, acc.x);
      acc.y = fmaf(x[k], wv.y, acc.y);
      acc.z = fmaf(x[k], wv.z, acc.z);
      acc.w = fmaf(x[k], wv.w, acc.w);
    }
    if (p == 0) {
      if (ob < 4) ((float4*)(Ps + (size_t)n * EF))[ob] = acc;
      else        ((float4*)(Pd + (size_t)n * EF))[ob - 4] = acc;
    } else {
      ((float4*)(hpart + (size_t)n * NF))[ob] = acc;
    }
  }
}

// ---------------------------------------------------------------------------
// Fused iteration i (1..11), e ping-pong eA -> eB. Three phases:
//  A) edge: eB[q] = sigmoid(bcomb + eA[q]@Wcomb + Ps[src] + Pd[dst])
//     (j-outer 4-wide, outer loop NOT unrolled -> ~40 live VGPRs)
//  B) node-z: z = hpart* (p0) | 0 (p1) + segsum(eA)@Wnc, two 16-wide halves,
//     shfl-combine pairs, sigmoid -> LDS sig table (+deg)
//  C) projection: nloc*16 independent 4-wide blocks across all 256 threads;
//     b<8 -> Ps|Pd (WSD), b>=8 -> hpart* (WnB, +deg*bvec refolded)
// No launch-bounds cap (R7 lesson: forced caps -> spills -> 250 MB/iter).
// ---------------------------------------------------------------------------
__global__ void __launch_bounds__(TPB) iter_kernel(
    const float* __restrict__ eA, float* __restrict__ eB,
    const unsigned short* __restrict__ src_s,
    const unsigned short* __restrict__ dst_s,
    const int* __restrict__ off, const int* __restrict__ bnd,
    const float* __restrict__ wbuf, float* __restrict__ hpart,
    const float* __restrict__ PsR, const float* __restrict__ PdR,
    float* __restrict__ PsW, float* __restrict__ PdW) {
  __shared__ float sW[WBUF_N];                 // 12.8 KB
  __shared__ float sSig[MAXN_CHUNK * SIG_LD];  // 11.5 KB
  const int tid = threadIdx.x, w = blockIdx.x;
  const int nstart = bnd[w], nend = bnd[w + 1];
  const int estart = off[nstart];
  const int eend = off[nend];
  const int nloc = nend - nstart;
  for (int i = tid; i < WBUF_N; i += TPB) sW[i] = wbuf[i];
  __syncthreads();

  // ---- A) edge phase ----
  for (int q = estart + tid; q < eend; q += TPB) {
    const int s = src_s[q], d = dst_s[q];
    const float4* ep  = (const float4*)(eA + (size_t)q * EF);
    float e[16];
#pragma unroll
    for (int k4 = 0; k4 < 4; ++k4) {
      float4 v = ep[k4];
      e[4 * k4] = v.x; e[4 * k4 + 1] = v.y; e[4 * k4 + 2] = v.z; e[4 * k4 + 3] = v.w;
    }
    const float4* psp = (const float4*)(PsR + (size_t)s * EF);
    const float4* pdp = (const float4*)(PdR + (size_t)d * EF);
    float4* ob = (float4*)(eB + (size_t)q * EF);
#pragma unroll 1
    for (int i4 = 0; i4 < 4; ++i4) {
      float4 bc = *(const float4*)(sW + B_COMB + 4 * i4);
      float4 a = psp[i4], b = pdp[i4];
      float4 z;
      z.x = bc.x + a.x + b.x;
      z.y = bc.y + a.y + b.y;
      z.z = bc.z + a.z + b.z;
      z.w = bc.w + a.w + b.w;
#pragma unroll
      for (int k = 0; k < EF; ++k) {
        float4 wv = *(const float4*)(sW + W_COMB + k * EF + 4 * i4);
        z.x = fmaf(e[k], wv.x, z.x);
        z.y = fmaf(e[k], wv.y, z.y);
        z.z = fmaf(e[k], wv.z, z.z);
        z.w = fmaf(e[k], wv.w, z.w);
      }
      z.x = sigmoidf_(z.x); z.y = sigmoidf_(z.y);
      z.z = sigmoidf_(z.z); z.w = sigmoidf_(z.w);
      ob[i4] = z;
    }
  }

  // ---- B/C) node phases, chunked by MAXN_CHUNK (typ. one chunk) ----
  const int p = tid & 1;
  for (int base = 0; base < nloc; base += MAXN_CHUNK) {
    const int cnum = min(MAXN_CHUNK, nloc - base);

    // B) z-phase: pair (2 lanes) per node, z in two 16-wide halves
    {
      const int ln = tid >> 1;   // 0..127 ; cnum <= 80 so one pass
      if (ln < cnum) {
        const int n = nstart + base + ln;
        const int o0 = off[n], o1 = off[n + 1];
        float s8[8] = {0, 0, 0, 0, 0, 0, 0, 0};
        const float* ebase = eA + 8 * p;
        for (int q = o0; q < o1; ++q) {
          const float4* e0 = (const float4*)(ebase + (size_t)q * EF);
          float4 a = e0[0], b = e0[1];
          s8[0] += a.x; s8[1] += a.y; s8[2] += a.z; s8[3] += a.w;
          s8[4] += b.x; s8[5] += b.y; s8[6] += b.z; s8[7] += b.w;
        }
        if (p == 0) sSig[ln * SIG_LD + 32] = (float)(o1 - o0);   // deg
#pragma unroll 1
        for (int h = 0; h < 2; ++h) {
          float zh[16];
          if (p == 0) {
            const float4* hp = (const float4*)(hpart + (size_t)n * NF + 16 * h);
#pragma unroll
            for (int j4 = 0; j4 < 4; ++j4) {
              float4 v = hp[j4];
              zh[4 * j4] = v.x; zh[4 * j4 + 1] = v.y;
              zh[4 * j4 + 2] = v.z; zh[4 * j4 + 3] = v.w;
            }
          } else {
#pragma unroll
            for (int j = 0; j < 16; ++j) zh[j] = 0.0f;
          }
#pragma unroll
          for (int k = 0; k < 8; ++k) {
            float v = s8[k];
            const float4* wr = (const float4*)(sW + W_NC + (8 * p + k) * NF + 16 * h);
#pragma unroll
            for (int j4 = 0; j4 < 4; ++j4) {
              float4 wv = wr[j4];
              zh[4 * j4 + 0] = fmaf(v, wv.x, zh[4 * j4 + 0]);
              zh[4 * j4 + 1] = fmaf(v, wv.y, zh[4 * j4 + 1]);
              zh[4 * j4 + 2] = fmaf(v, wv.z, zh[4 * j4 + 2]);
              zh[4 * j4 + 3] = fmaf(v, wv.w, zh[4 * j4 + 3]);
            }
          }
#pragma unroll
          for (int j = 0; j < 16; ++j) zh[j] += __shfl_xor(zh[j], 1, 64);
#pragma unroll
          for (int j = 0; j < 16; ++j) zh[j] = sigmoidf_(zh[j]);
          // lane p writes zh[8p..8p+8) -> sSig[ln][16h + 8p ..]
          float4* sp = (float4*)(sSig + ln * SIG_LD + 16 * h + 8 * p);
          sp[0] = make_float4(zh[8 * p + 0], zh[8 * p + 1], zh[8 * p + 2], zh[8 * p + 3]);
          sp[1] = make_float4(zh[8 * p + 4], zh[8 * p + 5], zh[8 * p + 6], zh[8 * p + 7]);
        }
      }
    }
    __syncthreads();   // sig table complete

    // C) projection: items = cnum * 16 four-wide output blocks
    const int items = cnum * 16;
    for (int it = tid; it < items; it += TPB) {
      const int ln = it >> 4, b = it & 15;
      const int n = nstart + base + ln;
      const float* sig = sSig + ln * SIG_LD;
      const int isH = (b >> 3);            // 0: WSD->Ps|Pd, 1: WnB->hpart
      const int ob = b & 7;
      const float* wb = sW + W_SD + isH * 1024 + 4 * ob;
      float4 acc = *(const float4*)(sW + B_SD + isH * 32 + 4 * ob);
      if (isH) {
        float dg = sig[32];
        float4 bv = *(const float4*)(sW + B_VEC + 4 * ob);
        acc.x = fmaf(dg, bv.x, acc.x); acc.y = fmaf(dg, bv.y, acc.y);
        acc.z = fmaf(dg, bv.z, acc.z); acc.w = fmaf(dg, bv.w, acc.w);
      }
#pragma unroll
      for (int k = 0; k < NF; ++k) {
        float4 wv = *(const float4*)(wb + k * NF);
        float v = sig[k];
        acc.x = fmaf(v, wv.x, acc.x);
        acc.y = fmaf(v, wv.y, acc.y);
        acc.z = fmaf(v, wv.z, acc.z);
        acc.w = fmaf(v, wv.w, acc.w);
      }
      if (isH) {
        ((float4*)(hpart + (size_t)n * NF))[ob] = acc;
      } else if (ob < 4) {
        ((float4*)(PsW + (size_t)n * EF))[ob] = acc;
      } else {
        ((float4*)(PdW + (size_t)n * EF))[ob - 4] = acc;
      }
    }
    __syncthreads();   // before next chunk reuses sSig
  }
}

// ---------------------------------------------------------------------------
// Final: node pass 12 + output head. Grid-wide 2 threads/node; reads e(12).
// hpart already contains deg*bvec (folded).
// ---------------------------------------------------------------------------
__global__ void __launch_bounds__(256) final12_kernel(
    const float* __restrict__ e_buf, const float* __restrict__ hpart,
    const int* __restrict__ off, const float* __restrict__ wbuf,
    float* __restrict__ out) {
  __shared__ float sW[WBUF_N];
  for (int i = threadIdx.x; i < WBUF_N; i += 256) sW[i] = wbuf[i];
  __syncthreads();
  int gid = blockIdx.x * 256 + threadIdx.x;
  int n = gid >> 1, p = gid & 1;
  if (n >= N_NODES) return;
  int o0 = off[n], o1 = off[n + 1];

  float s8[8] = {0, 0, 0, 0, 0, 0, 0, 0};
  for (int q = o0; q < o1; ++q) {
    const float4* ep = (const float4*)(e_buf + (size_t)q * EF + 8 * p);
    float4 a = ep[0], b = ep[1];
    s8[0] += a.x; s8[1] += a.y; s8[2] += a.z; s8[3] += a.w;
    s8[4] += b.x; s8[5] += b.y; s8[6] += b.z; s8[7] += b.w;
  }
  float z[NF];
  if (p == 0) {
    const float4* hp = (const float4*)(hpart + (size_t)n * NF);
#pragma unroll
    for (int j4 = 0; j4 < 8; ++j4) {
      float4 v = hp[j4];
      z[4 * j4] = v.x; z[4 * j4 + 1] = v.y; z[4 * j4 + 2] = v.z; z[4 * j4 + 3] = v.w;
    }
  } else {
#pragma unroll
    for (int j = 0; j < NF; ++j) z[j] = 0.0f;
  }
#pragma unroll
  for (int k = 0; k < 8; ++k) {
    float v = s8[k];
    const float4* wr = (const float4*)(sW + W_NC + (8 * p + k) * NF);
#pragma unroll
    for (int j4 = 0; j4 < 8; ++j4) {
      float4 wv = wr[j4];
      z[4 * j4 + 0] = fmaf(v, wv.x, z[4 * j4 + 0]);
      z[4 * j4 + 1] = fmaf(v, wv.y, z[4 * j4 + 1]);
      z[4 * j4 + 2] = fmaf(v, wv.z, z[4 * j4 + 2]);
      z[4 * j4 + 3] = fmaf(v, wv.w, z[4 * j4 + 3]);
    }
  }
#pragma unroll
  for (int j = 0; j < NF; ++j) z[j] += __shfl_xor(z[j], 1, 64);
#pragma unroll
  for (int j = 0; j < NF; ++j) z[j] = sigmoidf_(z[j]);

  // head: out = sig @ Wnf + bnf; each lane does its 16 rows (constant indices).
  float o[NC];
#pragma unroll
  for (int c = 0; c < NC; ++c) o[c] = (p == 0) ? sW[B_NF + c] : 0.0f;
#pragma unroll
  for (int k = 0; k < 16; ++k) {
    float v = (p == 0) ? z[k] : z[16 + k];
    const float* wr = sW + W_NF + (16 * p + k) * NC;
#pragma unroll
    for (int c = 0; c < NC; ++c) o[c] = fmaf(v, wr[c], o[c]);
  }
#pragma unroll
  for (int c = 0; c < NC; ++c) o[c] += __shfl_xor(o[c], 1, 64);
  if (p == 0) {
    float4* op = (float4*)(out + (size_t)n * NC);
    op[0] = make_float4(o[0], o[1], o[2], o[3]);
    op[1] = make_float4(o[4], o[5], o[6], o[7]);
  }
}

// ---------------------------------------------------------------------------
extern "C" void kernel_launch(void* const* d_in, const int* in_sizes, int n_in,
                              void* d_out, int out_size, void* d_ws, size_t ws_size,
                              hipStream_t stream) {
  const float* node_feat = (const float*)d_in[0];
  const float* edge_feat = (const float*)d_in[1];
  const int*   src = (const int*)d_in[2];
  const int*   dst = (const int*)d_in[3];
  const float* Wn  = (const float*)d_in[4];
  const float* bn  = (const float*)d_in[5];
  const float* We  = (const float*)d_in[6];
  const float* be  = (const float*)d_in[7];
  const float* Wem = (const float*)d_in[8];
  const float* bem = (const float*)d_in[9];
  const float* Wnm = (const float*)d_in[10];
  const float* bnm = (const float*)d_in[11];
  const float* Wfc = (const float*)d_in[12];
  const float* bfc = (const float*)d_in[13];
  float* out = (float*)d_out;

  float* ws    = (float*)d_ws;
  float* eb0   = ws;                                   // 3,840,000 f
  float* eb1   = eb0 + (size_t)N_EDGES * EF;           // 3,840,000 f
  float* hpart = eb1 + (size_t)N_EDGES * EF;           //   960,000 f
  float* Ps0   = hpart + (size_t)N_NODES * NF;         //   480,000 f
  float* Ps1   = Ps0 + (size_t)N_NODES * EF;
  float* Pd0   = Ps1 + (size_t)N_NODES * EF;
  float* Pd1   = Pd0 + (size_t)N_NODES * EF;
  float* wbuf  = Pd1 + (size_t)N_NODES * EF;           //     4,096 f
  int* cnt     = (int*)(wbuf + 4096);                  //    30,000 i
  int* off     = cnt + N_NODES;                        //    30,001 i
  int* cursor  = off + N_NODES + 1;                    //    30,000 i
  int* bnd     = cursor + N_NODES;                     //  NWG+1 i
  unsigned short* src_s = (unsigned short*)(bnd + NWG + 1);     // 240,000 u16
  unsigned short* dst_s = src_s + N_EDGES;                      // 240,000 u16
  float* PsA[2] = {Ps0, Ps1};
  float* PdA[2] = {Pd0, Pd1};
  float* EB2[2] = {eb0, eb1};

  const int EBg = (N_EDGES + 255) / 256;       // 938
  const int NB2 = (2 * N_NODES + 255) / 256;   // 235

  // counting sort of edges by dst + partition + weight folding
  hipMemsetAsync(cnt, 0, (size_t)N_NODES * sizeof(int), stream);
  hist_kernel<<<EBg, 256, 0, stream>>>(dst, cnt);
  scan_kernel<<<1, 1024, 0, stream>>>(cnt, off, cursor);
  scatter_kernel<<<EBg, 256, 0, stream>>>(edge_feat, src, dst, cursor,
                                          src_s, dst_s, eb0);
  partition_kernel<<<1, 1024, 0, stream>>>(off, bnd);
  precompute_kernel<<<1, 256, 0, stream>>>(Wn, bn, We, be, Wem, bem,
                                           Wnm, bnm, Wfc, bfc, wbuf);
  init_proj_kernel<<<NB2, 256, 0, stream>>>(node_feat, wbuf, off, Ps1, Pd1, hpart);

  // iterations 1..11: e ping-pong (iter i reads EB2[(i-1)&1], writes EB2[i&1]);
  // P ping-pong (reads P[i&1], writes P[(i+1)&1]). Then node 12 + head.
  for (int i = 1; i <= 11; ++i) {
    iter_kernel<<<NWG, TPB, 0, stream>>>(
        EB2[(i - 1) & 1], EB2[i & 1], src_s, dst_s, off, bnd, wbuf, hpart,
        PsA[i & 1], PdA[i & 1], PsA[(i + 1) & 1], PdA[(i + 1) & 1]);
  }
  final12_kernel<<<NB2, 256, 0, stream>>>(EB2[1], hpart, off, wbuf, out);
}